// Round 15
// baseline (428.264 us; speedup 1.0000x reference)
//
#include <hip/hip_runtime.h>
#include <math.h>

// Problem constants
#define TX 6
#define NB 2
#define NSTA 35
#define PPLANE 1296      // 36*36 padded plane
#define PADW 36

typedef __attribute__((ext_vector_type(8))) _Float16 half8;
typedef __attribute__((ext_vector_type(4))) float f32x4;

__device__ __forceinline__ float sigf(float x) { return 1.0f / (1.0f + __expf(-x)); }

// Async global->LDS DMA, 16B per lane. LDS dest is wave-uniform base + lane*16.
__device__ __forceinline__ void gload_lds16(const void* g, void* l) {
    __builtin_amdgcn_global_load_lds(
        (const __attribute__((address_space(1))) void*)g,
        (__attribute__((address_space(3))) void*)l, 16, 0, 0);
}

// ---------------------------------------------------------------------------
// Weight prep element: W (4CH,CTOT,5,5) fp32 gate-block-major ->
// Wk[d][mb][c32][lk][l16][e8] f16 : fragment = 512 f16 (16 m-rows x 32 cin).
// ---------------------------------------------------------------------------
template <int CTOT, int CTOTP, int CH>
__device__ __forceinline__ void prep_elem(int i, const float* __restrict__ W,
                                          _Float16* __restrict__ Wk) {
    constexpr int M = 4 * CH;
    const int e   = i & 7;
    const int l16 = (i >> 3) & 15;
    const int lk  = (i >> 7) & 3;
    const int c32 = (i >> 9) % (CTOTP / 32);
    const int rest = (i >> 9) / (CTOTP / 32);
    const int mb = rest % (M / 16);
    const int d  = rest / (M / 16);
    const int m = mb * 16 + l16;
    const int cin = c32 * 32 + lk * 8 + e;
    const int hc = m >> 2, g = m & 3;
    float v = 0.f;
    if (cin < CTOT) v = W[((g * CH + hc) * CTOT + cin) * 25 + d];
    Wk[i] = (_Float16)v;
}

// ---------------------------------------------------------------------------
// Fused prep: all three weight repacks + stage_x(0). One dispatch.
// Block ranges: [0,3200) Wk1, [3200,12800) Wk2, [12800,25600) Wk3,
// [25600,25728) stage x(0) into T1 (stride 128).
// ---------------------------------------------------------------------------
__global__ __launch_bounds__(256) void prep_all(
    const float* __restrict__ W1, _Float16* __restrict__ Wk1,
    const float* __restrict__ W2, _Float16* __restrict__ Wk2,
    const float* __restrict__ W3, _Float16* __restrict__ Wk3,
    const float* __restrict__ X, _Float16* __restrict__ T1) {
    const int bx = blockIdx.x;
    if (bx < 3200)  { prep_elem<75, 128, 64>(bx * 256 + threadIdx.x, W1, Wk1); return; }
    if (bx < 12800) { prep_elem<192, 192, 128>((bx - 3200) * 256 + threadIdx.x, W2, Wk2); return; }
    if (bx < 25600) { prep_elem<256, 256, 128>((bx - 12800) * 256 + threadIdx.x, W3, Wk3); return; }
    const int i = (bx - 25600) * 256 + threadIdx.x;
    const int c = i & 15, pix = (i >> 4) & 1023, b = i >> 14;
    if (c >= 11 || b >= NB) return;
    const int y = pix >> 5, x = pix & 31;
    T1[((size_t)(b * PPLANE) + (y + 2) * PADW + (x + 2)) * 128 + c] =
        (_Float16)X[(((b * TX + 0) * 11 + c) << 10) + pix];
}

// ---------------------------------------------------------------------------
// MFMA ConvLSTM cell v8: 4-way K-split, 1024 threads (r15 change).
// 16 waves/CU = 4 waves/SIMD (2x the r13 TLP) with UNCHANGED per-wave tap
// structure and total traffic. Group g (waves 4g..4g+3) does chunks
// c = 4i+g; inactive iterations still hit barriers (uniform count).
// 8 LDS buffers of 14336B (group g: 2g + (i&1)); slot = (rr*4+c8)*36+col,
// DMA decode = inverse. A-ring PDA=5 (25%5==0), cross-chunk refill cc=c+4.
// 3 partial-acc LDS writes + group-0 reduce and epilogue.
// ---------------------------------------------------------------------------
template <int CTOTP, int CH, int NM>
__device__ __forceinline__ void cell8_body(
    char* smem, int bid, int tid,
    const _Float16* __restrict__ T, const _Float16* __restrict__ Wk,
    const float* __restrict__ Bias, float* __restrict__ Cst,
    _Float16* __restrict__ outA, int strideA,
    _Float16* __restrict__ outB, int strideB, float* __restrict__ outP) {
    constexpr int M = 4 * CH;
    constexpr int NCH = CTOTP / 32;
    constexpr int NITER = (NCH + 3) / 4;
    constexpr int PDA = 5;

    const int wave = tid >> 6, lane = tid & 63;
    const int l16 = lane & 15, lk = lane >> 4;
    const int grp = wave >> 2, w2 = wave & 3;
    const int wm = w2 >> 1, wn = w2 & 1;
    const int mtile = bid % NM;
    const int ntile = bid / NM;
    const int nbase = ntile * 64;
    const int b = nbase >> 10;
    const int y0 = (nbase & 1023) >> 5;
    const _Float16* Tb = T + (size_t)(b * PPLANE) * CTOTP;

    f32x4 acc[2][2] = {};

    int bbase[2];
#pragma unroll
    for (int nt = 0; nt < 2; ++nt) {
        const int pxl = wn * 32 + nt * 16 + l16;
        const int r = pxl >> 5, x = pxl & 31;
        bbase[nt] = (((r * 4 + lk) * 36) + x) * 16;
    }
    const int laneAoff = lk * 128 + l16 * 8;

    auto loadA = [&](int cc, int dd, int mt) -> half8 {
        const int mb = mtile * 4 + wm * 2 + mt;
        return *(const half8*)(Wk +
            (size_t)(((dd * (M / 16) + mb) * NCH + cc) * 512 + laneAoff));
    };
    auto stage = [&](int c32, int bi) {
        char* dst = smem + bi * 14336;
#pragma unroll
        for (int k = 0; k < 4; ++k) {
            const int s = w2 + k * 4;
            if (s < 14) {
                const int idx = (s << 6) + lane;
                const int col = idx % 36;
                const int rc  = idx / 36;          // rc=24: pad, unread, in-ws
                const int c8 = rc & 3, rr = rc >> 2;
                const _Float16* src = Tb +
                    (size_t)((y0 + rr) * PADW + col) * CTOTP + c32 * 32 + c8 * 8;
                gload_lds16(src, dst + idx * 16);
            }
        }
    };

    // A-ring prologue: taps 0..4 of this group's first chunk (= grp < NCH)
    half8 apre[PDA][2];
#pragma unroll
    for (int p = 0; p < PDA; ++p) {
        apre[p][0] = loadA(grp, p, 0);
        apre[p][1] = loadA(grp, p, 1);
    }
    stage(grp, grp * 2);
    __syncthreads();

    for (int i = 0; i < NITER; ++i) {
        const int c = 4 * i + grp;
        const bool act = (c < NCH);
        if (act && c + 4 < NCH) stage(c + 4, grp * 2 + ((i + 1) & 1));
        const char* sb = smem + (grp * 2 + (i & 1)) * 14336;
        if (act) {
            half8 bpre[3][2];
#pragma unroll
            for (int p = 0; p < 3; ++p) {
                const int dy = p / 5, dx = p % 5;
                bpre[p][0] = *(const half8*)(sb + bbase[0] + (dy * 144 + dx) * 16);
                bpre[p][1] = *(const half8*)(sb + bbase[1] + (dy * 144 + dx) * 16);
            }
#pragma unroll
            for (int d = 0; d < 25; ++d) {
                const half8 a0 = apre[d % PDA][0];
                const half8 a1 = apre[d % PDA][1];
                const half8 b0 = bpre[d % 3][0];
                const half8 b1 = bpre[d % 3][1];
                {
                    const int dp = d + PDA;
                    const int cstep = dp / 25;          // static 0/1
                    const int dd = dp % 25;             // static
                    if (cstep == 0 || c + 4 < NCH) {
                        const int cc = c + 4 * cstep;   // group stride 4
                        apre[d % PDA][0] = loadA(cc, dd, 0);
                        apre[d % PDA][1] = loadA(cc, dd, 1);
                    }
                }
                if (d + 3 < 25) {
                    const int dy = (d + 3) / 5, dx = (d + 3) % 5;
                    bpre[d % 3][0] = *(const half8*)(sb + bbase[0] + (dy * 144 + dx) * 16);
                    bpre[d % 3][1] = *(const half8*)(sb + bbase[1] + (dy * 144 + dx) * 16);
                }
                acc[0][0] = __builtin_amdgcn_mfma_f32_16x16x32_f16(a0, b0, acc[0][0], 0, 0, 0);
                acc[0][1] = __builtin_amdgcn_mfma_f32_16x16x32_f16(a0, b1, acc[0][1], 0, 0, 0);
                acc[1][0] = __builtin_amdgcn_mfma_f32_16x16x32_f16(a1, b0, acc[1][0], 0, 0, 0);
                acc[1][1] = __builtin_amdgcn_mfma_f32_16x16x32_f16(a1, b1, acc[1][1], 0, 0, 0);
            }
        }
        __syncthreads();
    }

    // Cross-group reduction: groups 1..3 write partials (48KB in slab).
    float* red = (float*)smem;
    const int tig = tid & 255;
    if (grp > 0) {
        float* dst = red + (grp - 1) * 4096 + tig * 16;
#pragma unroll
        for (int mt = 0; mt < 2; ++mt)
#pragma unroll
            for (int nt = 0; nt < 2; ++nt)
                *(f32x4*)(dst + (mt * 2 + nt) * 4) = acc[mt][nt];
    }
    __syncthreads();
    if (grp > 0) return;
#pragma unroll
    for (int g = 0; g < 3; ++g)
#pragma unroll
        for (int mt = 0; mt < 2; ++mt)
#pragma unroll
            for (int nt = 0; nt < 2; ++nt)
                acc[mt][nt] += *(const f32x4*)(red + g * 4096 + tig * 16 + (mt * 2 + nt) * 4);

    // Epilogue (group 0): lane-local LSTM update.
#pragma unroll
    for (int mt = 0; mt < 2; ++mt) {
        const int hc = mtile * 16 + wm * 8 + mt * 4 + lk;
        const float bi = Bias[hc], bf = Bias[CH + hc];
        const float bo = Bias[2 * CH + hc], bg = Bias[3 * CH + hc];
#pragma unroll
        for (int nt = 0; nt < 2; ++nt) {
            const int pxl = wn * 32 + nt * 16 + l16;
            const int pix = (nbase & 1023) + pxl;
            const int y = pix >> 5, x = pix & 31;
            const f32x4 a = acc[mt][nt];
            const float gi = a[0] + bi, gf = a[1] + bf;
            const float go = a[2] + bo, gg = a[3] + bg;
            const int idx = ((b * CH + hc) << 10) + pix;
            const float c_old = Cst[idx];
            const float cn = sigf(gf) * c_old + sigf(gi) * tanhf(gg);
            const float hn = sigf(go) * tanhf(cn);
            Cst[idx] = cn;
            const _Float16 hh = (_Float16)hn;
            const size_t pp = (size_t)(b * PPLANE) + (y + 2) * PADW + (x + 2);
            outA[pp * strideA + hc] = hh;
            if (outB) outB[pp * strideB + hc] = hh;
            if (outP) outP[idx] = hn;
        }
    }
}

// Plain cell8 kernel (cell1(0), cell2)
template <int CTOTP, int CH, int NM>
__global__ __launch_bounds__(1024) void cell8_kernel(
    const _Float16* __restrict__ T, const _Float16* __restrict__ Wk,
    const float* __restrict__ Bias, float* __restrict__ Cst,
    _Float16* __restrict__ outA, int strideA,
    _Float16* __restrict__ outB, int strideB, float* __restrict__ outP) {
    __shared__ char smem[114688];
    cell8_body<CTOTP, CH, NM>(smem, blockIdx.x, threadIdx.x, T, Wk, Bias, Cst,
                              outA, strideA, outB, strideB, outP);
}

// cell8 + fused stage-x(tnext): extra 22 blocks write T1dst ch0..10
// (stride 128) — disjoint from everything cell3 touches.
template <int CTOTP, int CH, int NM>
__global__ __launch_bounds__(1024) void cell8_stage_kernel(
    const _Float16* __restrict__ T, const _Float16* __restrict__ Wk,
    const float* __restrict__ Bias, float* __restrict__ Cst,
    _Float16* __restrict__ outA, int strideA, float* __restrict__ outP,
    const float* __restrict__ X, _Float16* __restrict__ T1dst, int tnext) {
    __shared__ char smem[114688];
    const int bx = blockIdx.x;
    if (bx >= NM * 32) {
        if (tnext < TX) {
            const int idx = (bx - NM * 32) * 1024 + threadIdx.x;  // < 22528
            const int b = idx / 11264;
            const int r = idx - b * 11264;
            const int c = r >> 10, pix = r & 1023;
            const int y = pix >> 5, x = pix & 31;
            T1dst[((size_t)(b * PPLANE) + (y + 2) * PADW + (x + 2)) * 128 + c] =
                (_Float16)X[(((b * TX + tnext) * 11 + c) << 10) + pix];
        }
        return;
    }
    cell8_body<CTOTP, CH, NM>(smem, bx, threadIdx.x, T, Wk, Bias, Cst,
                              outA, strideA, nullptr, 0, outP);
}

// ---------------------------------------------------------------------------
// tail kernel (1024 thr): head(t) (aqi 70 + meo 10 blocks) + cell1(t+1)
// (128 blocks). cell1(t+1) reads T1[nxt] (h1(t) + x(t+1) staged previous
// dispatch); writes T1[cur]@11 and T2[nxt]@0 — race-free (r14-proven scheme).
// ---------------------------------------------------------------------------
__global__ __launch_bounds__(1024) void tail8_kernel(
    const float* __restrict__ H3, const float* __restrict__ Wm,
    const float* __restrict__ bm, const float* __restrict__ Wf1,
    const float* __restrict__ bf1, const float* __restrict__ Wf2,
    const float* __restrict__ bf2, const int* __restrict__ locs,
    float* __restrict__ out, int t,
    const _Float16* __restrict__ T1in, const _Float16* __restrict__ Wk1,
    const float* __restrict__ b1, float* __restrict__ C1,
    _Float16* __restrict__ h1outA, _Float16* __restrict__ h1outB,
    int do_cell1) {
    __shared__ char smem[114688];
    const int bx = blockIdx.x, tid = threadIdx.x;
    if (bx >= 80) {
        if (do_cell1)
            cell8_body<128, 64, 4>(smem, bx - 80, tid, T1in, Wk1, b1, C1,
                                   h1outA, 128, h1outB, 192, nullptr);
        return;
    }
    if (bx >= 70) {            // meo: 10 blocks
        const int idx = (bx - 70) * 1024 + tid;     // 0..10239
        const int b = idx / 5120, r = idx - b * 5120;
        const int oc = r >> 10, pix = r & 1023;
        const float* w = Wm + oc * 128;
        const float* h = H3 + ((b * 128) << 10) + pix;
        float a0 = 0.f, a1 = 0.f, a2 = 0.f, a3 = 0.f;
#pragma unroll
        for (int c = 0; c < 128; c += 4) {
            a0 = fmaf(w[c],     h[c << 10],       a0);
            a1 = fmaf(w[c + 1], h[(c + 1) << 10], a1);
            a2 = fmaf(w[c + 2], h[(c + 2) << 10], a2);
            a3 = fmaf(w[c + 3], h[(c + 3) << 10], a3);
        }
        out[2520 + (b * TX + t) * 5120 + r] = ((a0 + a1) + (a2 + a3)) + bm[oc];
        return;
    }
    // aqi: s = bx % 35, b = bx / 35; 4-way k-split (288 each) x 8 accs
    const int s = bx % NSTA, b = bx / NSTA;
    float* feats = (float*)smem;         // 1152
    float* psum  = feats + 1152;         // 4*256
    float* hid   = psum + 1024;          // 256
    const int y0 = locs[2 * s], x0 = locs[2 * s + 1];
    for (int k = tid; k < 1152; k += 1024) {
        const int c = k / 9, r = k % 9;
        feats[k] = H3[((b * 128 + c) << 10) + (y0 + r / 3) * 32 + (x0 + r % 3)];
    }
    __syncthreads();
    {
        const int h = tid & 255, kh = tid >> 8;
        const int kb = kh * 288;
        float ac[8] = {};
        for (int kk = 0; kk < 288; kk += 8) {
#pragma unroll
            for (int u = 0; u < 8; ++u)
                ac[u] = fmaf(feats[kb + kk + u], Wf1[(kb + kk + u) * 256 + h], ac[u]);
        }
        psum[kh * 256 + h] = ((ac[0] + ac[1]) + (ac[2] + ac[3])) +
                             ((ac[4] + ac[5]) + (ac[6] + ac[7]));
    }
    __syncthreads();
    if (tid < 256)
        hid[tid] = tanhf((psum[tid] + psum[256 + tid]) +
                         (psum[512 + tid] + psum[768 + tid]) + bf1[tid]);
    __syncthreads();
    if (tid < 6) {
        float ac[8] = {};
#pragma unroll
        for (int k = 0; k < 256; k += 8) {
#pragma unroll
            for (int u = 0; u < 8; ++u)
                ac[u] = fmaf(hid[k + u], Wf2[(k + u) * 6 + tid], ac[u]);
        }
        out[(b * TX + t) * 210 + s * 6 + tid] =
            ((ac[0] + ac[1]) + (ac[2] + ac[3])) +
            ((ac[4] + ac[5]) + (ac[6] + ac[7])) + bf2[tid];
    }
}

// ---------------------------------------------------------------------------
extern "C" void kernel_launch(void* const* d_in, const int* in_sizes, int n_in,
                              void* d_out, int out_size, void* d_ws, size_t ws_size,
                              hipStream_t stream) {
    const float* X   = (const float*)d_in[0];
    const float* W1  = (const float*)d_in[1];
    const float* b1  = (const float*)d_in[2];
    const float* W2  = (const float*)d_in[3];
    const float* b2  = (const float*)d_in[4];
    const float* W3  = (const float*)d_in[5];
    const float* b3  = (const float*)d_in[6];
    const float* Wm  = (const float*)d_in[7];
    const float* bm  = (const float*)d_in[8];
    const float* Wf1 = (const float*)d_in[9];
    const float* bf1 = (const float*)d_in[10];
    const float* Wf2 = (const float*)d_in[11];
    const float* bf2 = (const float*)d_in[12];
    const int* locs  = (const int*)d_in[13];
    float* out = (float*)d_out;

    // Byte-offset allocator, 256B aligned
    char* base = (char*)d_ws;
    size_t off = 0;
    auto alloc = [&](size_t bytes) -> char* {
        char* p = base + off;
        off = (off + bytes + 255) & ~(size_t)255;
        return p;
    };
    // Zeroed region: T buffers (f16; T1 stride 128), C states, H3
    _Float16* T1[2]; T1[0] = (_Float16*)alloc(2 * PPLANE * 128 * 2);
                     T1[1] = (_Float16*)alloc(2 * PPLANE * 128 * 2);
    _Float16* T2[2]; T2[0] = (_Float16*)alloc(2 * PPLANE * 192 * 2);
                     T2[1] = (_Float16*)alloc(2 * PPLANE * 192 * 2);
    _Float16* T3[2]; T3[0] = (_Float16*)alloc(2 * PPLANE * 256 * 2);
                     T3[1] = (_Float16*)alloc(2 * PPLANE * 256 * 2);
    float* C1 = (float*)alloc(2 * 64 * 1024 * 4);
    float* C2 = (float*)alloc(2 * 128 * 1024 * 4);
    float* C3 = (float*)alloc(2 * 128 * 1024 * 4);
    float* H3 = (float*)alloc(2 * 128 * 1024 * 4);
    const size_t zero_bytes = off;
    // Non-zeroed: fully written by prep each call (Wk1 padded to CTOTP=128)
    _Float16* Wk1 = (_Float16*)alloc((size_t)25 * 256 * 128 * 2);
    _Float16* Wk2 = (_Float16*)alloc((size_t)25 * 512 * 192 * 2);
    _Float16* Wk3 = (_Float16*)alloc((size_t)25 * 512 * 256 * 2);

    hipMemsetAsync(d_ws, 0, zero_bytes, stream);

    // Fused prep (3 weight repacks + stage x(0)) in one dispatch
    prep_all<<<dim3(25728), 256, 0, stream>>>(W1, Wk1, W2, Wk2, W3, Wk3, X, T1[0]);

    // cell1(0): T1[0] -> h1 to T1[1]@11 (stride 128) and T2[0]@0
    cell8_kernel<128, 64, 4><<<dim3(128), 1024, 0, stream>>>(
        T1[0], Wk1, b1, C1, T1[1] + 11, 128, T2[0] + 0, 192, nullptr);

    for (int t = 0; t < TX; ++t) {
        const int cur = t & 1, nxt = cur ^ 1;
        // cell2(t): T2[cur] -> T2[nxt]@64, T3[cur]@0
        cell8_kernel<192, 128, 8><<<dim3(256), 1024, 0, stream>>>(
            T2[cur], Wk2, b2, C2, T2[nxt] + 64, 192, T3[cur] + 0, 256, nullptr);
        // cell3(t) + stage x(t+1) into T1[nxt] ch0..10
        cell8_stage_kernel<256, 128, 8><<<dim3(278), 1024, 0, stream>>>(
            T3[cur], Wk3, b3, C3, T3[nxt] + 128, 256, H3, X, T1[nxt], t + 1);
        // head(t) + cell1(t+1)
        const int do_c1 = (t + 1 < TX);
        tail8_kernel<<<dim3(do_c1 ? 208 : 80), 1024, 0, stream>>>(
            H3, Wm, bm, Wf1, bf1, Wf2, bf2, locs, out, t,
            T1[nxt], Wk1, b1, C1, T1[cur] + 11, T2[nxt] + 0, do_c1);
    }
}

// Round 16
// 408.251 us; speedup vs baseline: 1.0490x; 1.0490x over previous
//
#include <hip/hip_runtime.h>
#include <math.h>

// Problem constants
#define TX 6
#define NB 2
#define NSTA 35
#define PPLANE 1296      // 36*36 padded plane
#define PADW 36

typedef __attribute__((ext_vector_type(8))) _Float16 half8;
typedef __attribute__((ext_vector_type(4))) float f32x4;

__device__ __forceinline__ float sigf(float x) { return 1.0f / (1.0f + __expf(-x)); }

// Async global->LDS DMA, 16B per lane. LDS dest is wave-uniform base + lane*16.
__device__ __forceinline__ void gload_lds16(const void* g, void* l) {
    __builtin_amdgcn_global_load_lds(
        (const __attribute__((address_space(1))) void*)g,
        (__attribute__((address_space(3))) void*)l, 16, 0, 0);
}

// ---------------------------------------------------------------------------
// Weight prep element: W (4CH,CTOT,5,5) fp32 gate-block-major ->
// Wk[d][mb][c32][lk][l16][e8] f16 : fragment = 512 f16 (16 m-rows x 32 cin).
// ---------------------------------------------------------------------------
template <int CTOT, int CTOTP, int CH>
__device__ __forceinline__ void prep_elem(int i, const float* __restrict__ W,
                                          _Float16* __restrict__ Wk) {
    constexpr int M = 4 * CH;
    const int e   = i & 7;
    const int l16 = (i >> 3) & 15;
    const int lk  = (i >> 7) & 3;
    const int c32 = (i >> 9) % (CTOTP / 32);
    const int rest = (i >> 9) / (CTOTP / 32);
    const int mb = rest % (M / 16);
    const int d  = rest / (M / 16);
    const int m = mb * 16 + l16;
    const int cin = c32 * 32 + lk * 8 + e;
    const int hc = m >> 2, g = m & 3;
    float v = 0.f;
    if (cin < CTOT) v = W[((g * CH + hc) * CTOT + cin) * 25 + d];
    Wk[i] = (_Float16)v;
}

// ---------------------------------------------------------------------------
// Fused prep: all three weight repacks + stage_x(0). One dispatch. (r15 proven)
// ---------------------------------------------------------------------------
__global__ __launch_bounds__(256) void prep_all(
    const float* __restrict__ W1, _Float16* __restrict__ Wk1,
    const float* __restrict__ W2, _Float16* __restrict__ Wk2,
    const float* __restrict__ W3, _Float16* __restrict__ Wk3,
    const float* __restrict__ X, _Float16* __restrict__ T1) {
    const int bx = blockIdx.x;
    if (bx < 3200)  { prep_elem<75, 128, 64>(bx * 256 + threadIdx.x, W1, Wk1); return; }
    if (bx < 12800) { prep_elem<192, 192, 128>((bx - 3200) * 256 + threadIdx.x, W2, Wk2); return; }
    if (bx < 25600) { prep_elem<256, 256, 128>((bx - 12800) * 256 + threadIdx.x, W3, Wk3); return; }
    const int i = (bx - 25600) * 256 + threadIdx.x;
    const int c = i & 15, pix = (i >> 4) & 1023, b = i >> 14;
    if (c >= 11 || b >= NB) return;
    const int y = pix >> 5, x = pix & 31;
    T1[((size_t)(b * PPLANE) + (y + 2) * PADW + (x + 2)) * 128 + c] =
        (_Float16)X[(((b * TX + 0) * 11 + c) << 10) + pix];
}

// ---------------------------------------------------------------------------
// MFMA ConvLSTM cell, generalized NG-way K-split (4 waves per group).
// NG must satisfy: NCH % NG == 0 for balance (r15 lesson: cell2 6-chunk at
// NG=4 idled half the block). NG=2 reduces exactly to the r13/r14-proven v7.
// Group g (waves 4g..4g+3) does chunks c = NG*i+g; 2 LDS buffers per group;
// slot = (rr*4+c8)*36+col, DMA decode = inverse; A-ring PDA=5 (25%5==0),
// cross-chunk refill stride NG; NG-1 partial-acc LDS writes, group-0 reduce
// + LSTM epilogue. smem >= 2*NG*14336 B.
// ---------------------------------------------------------------------------
template <int CTOTP, int CH, int NM, int NG>
__device__ __forceinline__ void cellN_body(
    char* smem, int bid, int tid,
    const _Float16* __restrict__ T, const _Float16* __restrict__ Wk,
    const float* __restrict__ Bias, float* __restrict__ Cst,
    _Float16* __restrict__ outA, int strideA,
    _Float16* __restrict__ outB, int strideB, float* __restrict__ outP) {
    constexpr int M = 4 * CH;
    constexpr int NCH = CTOTP / 32;
    constexpr int NITER = (NCH + NG - 1) / NG;
    constexpr int PDA = 5;

    const int wave = tid >> 6, lane = tid & 63;
    const int l16 = lane & 15, lk = lane >> 4;
    const int grp = wave >> 2, w2 = wave & 3;
    const int wm = w2 >> 1, wn = w2 & 1;
    const int mtile = bid % NM;
    const int ntile = bid / NM;
    const int nbase = ntile * 64;
    const int b = nbase >> 10;
    const int y0 = (nbase & 1023) >> 5;
    const _Float16* Tb = T + (size_t)(b * PPLANE) * CTOTP;

    f32x4 acc[2][2] = {};

    int bbase[2];
#pragma unroll
    for (int nt = 0; nt < 2; ++nt) {
        const int pxl = wn * 32 + nt * 16 + l16;
        const int r = pxl >> 5, x = pxl & 31;
        bbase[nt] = (((r * 4 + lk) * 36) + x) * 16;
    }
    const int laneAoff = lk * 128 + l16 * 8;

    auto loadA = [&](int cc, int dd, int mt) -> half8 {
        const int mb = mtile * 4 + wm * 2 + mt;
        return *(const half8*)(Wk +
            (size_t)(((dd * (M / 16) + mb) * NCH + cc) * 512 + laneAoff));
    };
    auto stage = [&](int c32, int bi) {
        char* dst = smem + bi * 14336;
#pragma unroll
        for (int k = 0; k < 4; ++k) {
            const int s = w2 + k * 4;
            if (s < 14) {
                const int idx = (s << 6) + lane;
                const int col = idx % 36;
                const int rc  = idx / 36;          // rc=24: pad, unread, in-ws
                const int c8 = rc & 3, rr = rc >> 2;
                const _Float16* src = Tb +
                    (size_t)((y0 + rr) * PADW + col) * CTOTP + c32 * 32 + c8 * 8;
                gload_lds16(src, dst + idx * 16);
            }
        }
    };

    // A-ring prologue: taps 0..4 of this group's first chunk (= grp < NCH)
    half8 apre[PDA][2];
#pragma unroll
    for (int p = 0; p < PDA; ++p) {
        apre[p][0] = loadA(grp, p, 0);
        apre[p][1] = loadA(grp, p, 1);
    }
    stage(grp, grp * 2);
    __syncthreads();

    for (int i = 0; i < NITER; ++i) {
        const int c = NG * i + grp;
        const bool act = (c < NCH);
        if (act && c + NG < NCH) stage(c + NG, grp * 2 + ((i + 1) & 1));
        const char* sb = smem + (grp * 2 + (i & 1)) * 14336;
        if (act) {
            half8 bpre[3][2];
#pragma unroll
            for (int p = 0; p < 3; ++p) {
                const int dy = p / 5, dx = p % 5;
                bpre[p][0] = *(const half8*)(sb + bbase[0] + (dy * 144 + dx) * 16);
                bpre[p][1] = *(const half8*)(sb + bbase[1] + (dy * 144 + dx) * 16);
            }
#pragma unroll
            for (int d = 0; d < 25; ++d) {
                const half8 a0 = apre[d % PDA][0];
                const half8 a1 = apre[d % PDA][1];
                const half8 b0 = bpre[d % 3][0];
                const half8 b1 = bpre[d % 3][1];
                {
                    const int dp = d + PDA;
                    const int cstep = dp / 25;          // static 0/1
                    const int dd = dp % 25;             // static
                    if (cstep == 0 || c + NG < NCH) {
                        const int cc = c + NG * cstep;  // group stride NG
                        apre[d % PDA][0] = loadA(cc, dd, 0);
                        apre[d % PDA][1] = loadA(cc, dd, 1);
                    }
                }
                if (d + 3 < 25) {
                    const int dy = (d + 3) / 5, dx = (d + 3) % 5;
                    bpre[d % 3][0] = *(const half8*)(sb + bbase[0] + (dy * 144 + dx) * 16);
                    bpre[d % 3][1] = *(const half8*)(sb + bbase[1] + (dy * 144 + dx) * 16);
                }
                acc[0][0] = __builtin_amdgcn_mfma_f32_16x16x32_f16(a0, b0, acc[0][0], 0, 0, 0);
                acc[0][1] = __builtin_amdgcn_mfma_f32_16x16x32_f16(a0, b1, acc[0][1], 0, 0, 0);
                acc[1][0] = __builtin_amdgcn_mfma_f32_16x16x32_f16(a1, b0, acc[1][0], 0, 0, 0);
                acc[1][1] = __builtin_amdgcn_mfma_f32_16x16x32_f16(a1, b1, acc[1][1], 0, 0, 0);
            }
        }
        __syncthreads();
    }

    // Cross-group reduction: groups 1..NG-1 write partials (16KB each).
    float* red = (float*)smem;
    const int tig = tid & 255;
    if (grp > 0) {
        float* dst = red + (grp - 1) * 4096 + tig * 16;
#pragma unroll
        for (int mt = 0; mt < 2; ++mt)
#pragma unroll
            for (int nt = 0; nt < 2; ++nt)
                *(f32x4*)(dst + (mt * 2 + nt) * 4) = acc[mt][nt];
    }
    __syncthreads();
    if (grp > 0) return;
#pragma unroll
    for (int g = 0; g < NG - 1; ++g)
#pragma unroll
        for (int mt = 0; mt < 2; ++mt)
#pragma unroll
            for (int nt = 0; nt < 2; ++nt)
                acc[mt][nt] += *(const f32x4*)(red + g * 4096 + tig * 16 + (mt * 2 + nt) * 4);

    // Epilogue (group 0): lane-local LSTM update.
#pragma unroll
    for (int mt = 0; mt < 2; ++mt) {
        const int hc = mtile * 16 + wm * 8 + mt * 4 + lk;
        const float bi = Bias[hc], bf = Bias[CH + hc];
        const float bo = Bias[2 * CH + hc], bg = Bias[3 * CH + hc];
#pragma unroll
        for (int nt = 0; nt < 2; ++nt) {
            const int pxl = wn * 32 + nt * 16 + l16;
            const int pix = (nbase & 1023) + pxl;
            const int y = pix >> 5, x = pix & 31;
            const f32x4 a = acc[mt][nt];
            const float gi = a[0] + bi, gf = a[1] + bf;
            const float go = a[2] + bo, gg = a[3] + bg;
            const int idx = ((b * CH + hc) << 10) + pix;
            const float c_old = Cst[idx];
            const float cn = sigf(gf) * c_old + sigf(gi) * tanhf(gg);
            const float hn = sigf(go) * tanhf(cn);
            Cst[idx] = cn;
            const _Float16 hh = (_Float16)hn;
            const size_t pp = (size_t)(b * PPLANE) + (y + 2) * PADW + (x + 2);
            outA[pp * strideA + hc] = hh;
            if (outB) outB[pp * strideB + hc] = hh;
            if (outP) outP[idx] = hn;
        }
    }
}

// cell1(0) kernel: NG=2, 512 thr (r14 config)
__global__ __launch_bounds__(512) void cell1_kernel(
    const _Float16* __restrict__ T, const _Float16* __restrict__ Wk,
    const float* __restrict__ Bias, float* __restrict__ Cst,
    _Float16* __restrict__ outA, _Float16* __restrict__ outB) {
    __shared__ char smem[57344];
    cellN_body<128, 64, 4, 2>(smem, blockIdx.x, threadIdx.x, T, Wk, Bias, Cst,
                              outA, 128, outB, 192, nullptr);
}

// cell2 kernel: NG=3, 768 thr (r16 change — balanced 6/3 split, 3 waves/SIMD)
__global__ __launch_bounds__(768) void cell2_kernel(
    const _Float16* __restrict__ T, const _Float16* __restrict__ Wk,
    const float* __restrict__ Bias, float* __restrict__ Cst,
    _Float16* __restrict__ outA, _Float16* __restrict__ outB) {
    __shared__ char smem[86016];
    cellN_body<192, 128, 8, 3>(smem, blockIdx.x, threadIdx.x, T, Wk, Bias, Cst,
                               outA, 192, outB, 256, nullptr);
}

// cell3 + fused stage-x(tnext): NG=2, 512 thr (r14 config)
__global__ __launch_bounds__(512) void cell3_stage_kernel(
    const _Float16* __restrict__ T, const _Float16* __restrict__ Wk,
    const float* __restrict__ Bias, float* __restrict__ Cst,
    _Float16* __restrict__ outA, float* __restrict__ outP,
    const float* __restrict__ X, _Float16* __restrict__ T1dst, int tnext) {
    __shared__ char smem[57344];
    const int bx = blockIdx.x;
    if (bx >= 256) {
        if (tnext < TX) {
            const int idx = (bx - 256) * 512 + threadIdx.x;  // < 22528
            const int b = idx / 11264;
            const int r = idx - b * 11264;
            const int c = r >> 10, pix = r & 1023;
            const int y = pix >> 5, x = pix & 31;
            T1dst[((size_t)(b * PPLANE) + (y + 2) * PADW + (x + 2)) * 128 + c] =
                (_Float16)X[(((b * TX + tnext) * 11 + c) << 10) + pix];
        }
        return;
    }
    cellN_body<256, 128, 8, 2>(smem, bx, threadIdx.x, T, Wk, Bias, Cst,
                               outA, 256, nullptr, 0, outP);
}

// ---------------------------------------------------------------------------
// tail kernel (512 thr, r14-proven): head(t) (90 blocks) + cell1(t+1)
// (128 blocks). Race-free per r14 dependency analysis.
// ---------------------------------------------------------------------------
__global__ __launch_bounds__(512) void tail_kernel(
    const float* __restrict__ H3, const float* __restrict__ Wm,
    const float* __restrict__ bm, const float* __restrict__ Wf1,
    const float* __restrict__ bf1, const float* __restrict__ Wf2,
    const float* __restrict__ bf2, const int* __restrict__ locs,
    float* __restrict__ out, int t,
    const _Float16* __restrict__ T1in, const _Float16* __restrict__ Wk1,
    const float* __restrict__ b1, float* __restrict__ C1,
    _Float16* __restrict__ h1outA, _Float16* __restrict__ h1outB,
    int do_cell1) {
    __shared__ char smem[57344];
    const int bx = blockIdx.x, tid = threadIdx.x;
    if (bx >= 90) {
        if (do_cell1)
            cellN_body<128, 64, 4, 2>(smem, bx - 90, tid, T1in, Wk1, b1, C1,
                                      h1outA, 128, h1outB, 192, nullptr);
        return;
    }
    const int b = bx / 45, hb = bx % 45;
    if (hb >= NSTA) {          // meo: 10 blocks per b
        const int idx = (hb - NSTA) * 512 + tid;
        const int oc = idx >> 10, pix = idx & 1023;
        const float* w = Wm + oc * 128;
        const float* h = H3 + ((b * 128) << 10) + pix;
        float a0 = 0.f, a1 = 0.f, a2 = 0.f, a3 = 0.f;
#pragma unroll
        for (int c = 0; c < 128; c += 4) {
            a0 = fmaf(w[c],     h[c << 10],       a0);
            a1 = fmaf(w[c + 1], h[(c + 1) << 10], a1);
            a2 = fmaf(w[c + 2], h[(c + 2) << 10], a2);
            a3 = fmaf(w[c + 3], h[(c + 3) << 10], a3);
        }
        out[2520 + (b * TX + t) * 5120 + idx] = ((a0 + a1) + (a2 + a3)) + bm[oc];
        return;
    }
    // aqi station s = hb (r12-proven: coalesced Wf1, 2-way k-split x16 accs)
    float* feats = (float*)smem;         // 1152
    float* psum  = feats + 1152;         // 2*256
    float* hid   = psum + 512;           // 256
    const int s = hb;
    const int y0 = locs[2 * s], x0 = locs[2 * s + 1];
    for (int k = tid; k < 1152; k += 512) {
        const int c = k / 9, r = k % 9;
        feats[k] = H3[((b * 128 + c) << 10) + (y0 + r / 3) * 32 + (x0 + r % 3)];
    }
    __syncthreads();
    {
        const int h = tid & 255, kh = tid >> 8;
        const int kb = kh * 576;
        float ac[16] = {};
        for (int kk = 0; kk < 576; kk += 16) {
#pragma unroll
            for (int u = 0; u < 16; ++u)
                ac[u] = fmaf(feats[kb + kk + u], Wf1[(kb + kk + u) * 256 + h], ac[u]);
        }
        psum[kh * 256 + h] = (((ac[0] + ac[1]) + (ac[2] + ac[3])) +
                              ((ac[4] + ac[5]) + (ac[6] + ac[7]))) +
                             (((ac[8] + ac[9]) + (ac[10] + ac[11])) +
                              ((ac[12] + ac[13]) + (ac[14] + ac[15])));
    }
    __syncthreads();
    if (tid < 256) hid[tid] = tanhf(psum[tid] + psum[256 + tid] + bf1[tid]);
    __syncthreads();
    if (tid < 6) {
        float ac[8] = {};
#pragma unroll
        for (int k = 0; k < 256; k += 8) {
#pragma unroll
            for (int u = 0; u < 8; ++u)
                ac[u] = fmaf(hid[k + u], Wf2[(k + u) * 6 + tid], ac[u]);
        }
        out[(b * TX + t) * 210 + s * 6 + tid] =
            ((ac[0] + ac[1]) + (ac[2] + ac[3])) +
            ((ac[4] + ac[5]) + (ac[6] + ac[7])) + bf2[tid];
    }
}

// ---------------------------------------------------------------------------
extern "C" void kernel_launch(void* const* d_in, const int* in_sizes, int n_in,
                              void* d_out, int out_size, void* d_ws, size_t ws_size,
                              hipStream_t stream) {
    const float* X   = (const float*)d_in[0];
    const float* W1  = (const float*)d_in[1];
    const float* b1  = (const float*)d_in[2];
    const float* W2  = (const float*)d_in[3];
    const float* b2  = (const float*)d_in[4];
    const float* W3  = (const float*)d_in[5];
    const float* b3  = (const float*)d_in[6];
    const float* Wm  = (const float*)d_in[7];
    const float* bm  = (const float*)d_in[8];
    const float* Wf1 = (const float*)d_in[9];
    const float* bf1 = (const float*)d_in[10];
    const float* Wf2 = (const float*)d_in[11];
    const float* bf2 = (const float*)d_in[12];
    const int* locs  = (const int*)d_in[13];
    float* out = (float*)d_out;

    // Byte-offset allocator, 256B aligned
    char* base = (char*)d_ws;
    size_t off = 0;
    auto alloc = [&](size_t bytes) -> char* {
        char* p = base + off;
        off = (off + bytes + 255) & ~(size_t)255;
        return p;
    };
    // Zeroed region: T buffers (f16; T1 stride 128), C states, H3
    _Float16* T1[2]; T1[0] = (_Float16*)alloc(2 * PPLANE * 128 * 2);
                     T1[1] = (_Float16*)alloc(2 * PPLANE * 128 * 2);
    _Float16* T2[2]; T2[0] = (_Float16*)alloc(2 * PPLANE * 192 * 2);
                     T2[1] = (_Float16*)alloc(2 * PPLANE * 192 * 2);
    _Float16* T3[2]; T3[0] = (_Float16*)alloc(2 * PPLANE * 256 * 2);
                     T3[1] = (_Float16*)alloc(2 * PPLANE * 256 * 2);
    float* C1 = (float*)alloc(2 * 64 * 1024 * 4);
    float* C2 = (float*)alloc(2 * 128 * 1024 * 4);
    float* C3 = (float*)alloc(2 * 128 * 1024 * 4);
    float* H3 = (float*)alloc(2 * 128 * 1024 * 4);
    const size_t zero_bytes = off;
    // Non-zeroed: fully written by prep each call (Wk1 padded to CTOTP=128)
    _Float16* Wk1 = (_Float16*)alloc((size_t)25 * 256 * 128 * 2);
    _Float16* Wk2 = (_Float16*)alloc((size_t)25 * 512 * 192 * 2);
    _Float16* Wk3 = (_Float16*)alloc((size_t)25 * 512 * 256 * 2);

    hipMemsetAsync(d_ws, 0, zero_bytes, stream);

    // Fused prep (3 weight repacks + stage x(0)) in one dispatch
    prep_all<<<dim3(25728), 256, 0, stream>>>(W1, Wk1, W2, Wk2, W3, Wk3, X, T1[0]);

    // cell1(0): T1[0] -> h1 to T1[1]@11 (stride 128) and T2[0]@0
    cell1_kernel<<<dim3(128), 512, 0, stream>>>(
        T1[0], Wk1, b1, C1, T1[1] + 11, T2[0] + 0);

    for (int t = 0; t < TX; ++t) {
        const int cur = t & 1, nxt = cur ^ 1;
        // cell2(t): NG=3/768thr. T2[cur] -> T2[nxt]@64, T3[cur]@0
        cell2_kernel<<<dim3(256), 768, 0, stream>>>(
            T2[cur], Wk2, b2, C2, T2[nxt] + 64, T3[cur] + 0);
        // cell3(t) + stage x(t+1) into T1[nxt] ch0..10
        cell3_stage_kernel<<<dim3(300), 512, 0, stream>>>(
            T3[cur], Wk3, b3, C3, T3[nxt] + 128, H3, X, T1[nxt], t + 1);
        // head(t) + cell1(t+1)
        const int do_c1 = (t + 1 < TX);
        tail_kernel<<<dim3(do_c1 ? 218 : 90), 512, 0, stream>>>(
            H3, Wm, bm, Wf1, bf1, Wf2, bf2, locs, out, t,
            T1[nxt], Wk1, b1, C1, T1[cur] + 11, T2[nxt] + 0, do_c1);
    }
}